// Round 5
// baseline (780.557 us; speedup 1.0000x reference)
//
#include <hip/hip_runtime.h>

#define NN 8192

typedef float v4f __attribute__((ext_vector_type(4)));

__device__ __forceinline__ v4f nt_load4(const float* p) {
    return __builtin_nontemporal_load((const v4f*)p);
}
__device__ __forceinline__ void nt_store4(float* p, v4f v) {
    __builtin_nontemporal_store(v, (v4f*)p);
}

// --- Kernel 1: z[j] = input[j] (workspace is poisoned each launch) ---
__global__ __launch_bounds__(256) void init_z(const float* __restrict__ input,
                                              float* __restrict__ z) {
    int j = blockIdx.x * 256 + threadIdx.x;
    z[j] = input[j];
}

// --- Kernel 2: partial matvec: z[j] += sum_i yin[i]*(w[i,j] + alpha[i,j]*hebb[i,j]) ---
// grid = (8 col-tiles, 512 row-chunks), block = 256, 4 cols/thread, 16 rows/block.
// ALL matrix loads nontemporal (R3's measured-fast config, 164 us): nt loads
// still HIT in L3 (hebb stays resident because hebb_update's regular read
// re-allocates it every iteration), but skip the L2-allocate path that cost
// +24 us in R4. matvec = pure consumer; hebb_update = the allocator.
__global__ __launch_bounds__(256) void matvec_partial(
    const float* __restrict__ yin,
    const float* __restrict__ w,
    const float* __restrict__ alpha,
    const float* __restrict__ hebb,
    float* __restrict__ z)
{
    const int j0 = blockIdx.x * 1024 + threadIdx.x * 4;
    const int i0 = blockIdx.y * 16;

    v4f s = {0.f, 0.f, 0.f, 0.f};
#pragma unroll 4
    for (int r = 0; r < 16; ++r) {
        const int i = i0 + r;
        const float y = yin[i];  // uniform per block iter -> scalar load
        const size_t base = (size_t)i * NN + (size_t)j0;
        const v4f wv = nt_load4(w + base);
        const v4f av = nt_load4(alpha + base);
        const v4f hv = nt_load4(hebb + base);   // nt: L3 hit, no L2 pollution
        s.x = fmaf(y, fmaf(av.x, hv.x, wv.x), s.x);
        s.y = fmaf(y, fmaf(av.y, hv.y, wv.y), s.y);
        s.z = fmaf(y, fmaf(av.z, hv.z, wv.z), s.z);
        s.w = fmaf(y, fmaf(av.w, hv.w, wv.w), s.w);
    }
    atomicAdd(&z[j0 + 0], s.x);
    atomicAdd(&z[j0 + 1], s.y);
    atomicAdd(&z[j0 + 2], s.z);
    atomicAdd(&z[j0 + 3], s.w);
}

// --- Kernel 3: yout[j] = tanh(z[j]) ---
__global__ __launch_bounds__(256) void tanh_k(const float* __restrict__ z,
                                              float* __restrict__ yout) {
    int j = blockIdx.x * 256 + threadIdx.x;
    yout[j] = tanhf(z[j]);
}

// --- Kernel 4: hebb_new[i,j] = (1-eta)*hebb[i,j] + eta*yin[i]*yout[j] ---
// 16384 blocks x 256 threads, 4 float4 per thread (coalesced within block).
// hebb read: REGULAR on purpose -- this is what keeps hebb L3-resident across
// iterations (serves both matvec and this kernel). hebb_out store: nontemporal
// (written once, never read; no write-allocate eviction pressure).
__global__ __launch_bounds__(256) void hebb_update(
    const float* __restrict__ hebb,
    const float* __restrict__ yin,
    const float* __restrict__ yout,
    const float* __restrict__ eta_p,
    float* __restrict__ hebb_out)
{
    const float eta = eta_p[0];
    const float om = 1.0f - eta;
    const size_t f0 = (size_t)blockIdx.x * 1024 + threadIdx.x;
#pragma unroll
    for (int k = 0; k < 4; ++k) {
        const size_t f = f0 + (size_t)k * 256;   // float4 index
        const size_t i = f >> 11;                // row (2048 float4 per row)
        const size_t j = (f & 2047) * 4;         // col
        const float ye = eta * yin[i];
        const v4f h  = *(const v4f*)(hebb + i * NN + j);
        const v4f yo = *(const v4f*)(yout + j);
        v4f o;
        o.x = fmaf(om, h.x, ye * yo.x);
        o.y = fmaf(om, h.y, ye * yo.y);
        o.z = fmaf(om, h.z, ye * yo.z);
        o.w = fmaf(om, h.w, ye * yo.w);
        nt_store4(hebb_out + i * NN + j, o);
    }
}

extern "C" void kernel_launch(void* const* d_in, const int* in_sizes, int n_in,
                              void* d_out, int out_size, void* d_ws, size_t ws_size,
                              hipStream_t stream) {
    const float* input = (const float*)d_in[0];   // [1, N]
    const float* yin   = (const float*)d_in[1];   // [1, N]
    const float* hebb  = (const float*)d_in[2];   // [N, N]
    const float* w     = (const float*)d_in[3];   // [N, N]
    const float* alpha = (const float*)d_in[4];   // [N, N]
    const float* eta   = (const float*)d_in[5];   // [1]

    float* yout_out = (float*)d_out;              // first N floats
    float* hebb_out = yout_out + NN;              // next N*N floats
    float* z = (float*)d_ws;                      // N floats scratch

    init_z<<<NN / 256, 256, 0, stream>>>(input, z);
    matvec_partial<<<dim3(8, 512), 256, 0, stream>>>(yin, w, alpha, hebb, z);
    tanh_k<<<NN / 256, 256, 0, stream>>>(z, yout_out);
    hebb_update<<<(NN * (size_t)NN) / 4096, 256, 0, stream>>>(hebb, yin, yout_out, eta, hebb_out);
}